// Round 5
// baseline (27075.552 us; speedup 1.0000x reference)
//
#include <hip/hip_runtime.h>
#include <hip/hip_fp16.h>
#include <math.h>

// EarthMoverDistance: exact Hungarian (JV successive shortest path).
// B=8, N=1024, 3-D Euclidean cost. One wave per batch; lane owns 16 columns
// (c = lane*16+k) in registers.
// R11 (base = R10, 23.1 ms = 21.6 jv + 1.5 pre):
//  - ARR semantics restored to R9's (2-pass, tie-displacement with
//    prefer-free, JV free[--k] on strict) — R9 proved this state gets
//    jv = 18.88 ms. R10's no-displacement variant was cheap but useless
//    on the tie-heavy fp16 matrix (jv back to 21.6).
//  - ARR per-iteration cost fixed: the 6-step __shfl_xor butterfly
//    (ds_permute ~120cy x ~18 serialized = ~1us/iter — the R9 10.4 ms) is
//    replaced by DPP wave_min argmin-with-payload (gm1 = wave_min(m1);
//    winner = first lane at gm1; gm2 = wave_min(lane==wl ? m2 : m1);
//    c1 = readlane(c1, wl)) and the local depth-16 (m1,m2,c1) chain by
//    4 depth-4 chains + pair merges. All comparison outcomes preserved
//    => ARR output state bit-identical to R9's; only its price drops.
//  - SSP kernel byte-identical to R10 (runner-up prefetch kept).
// Invariants (R7/R9/R10, absmax 0.0): duals only tighten, matched edges
// tight; stale u on displaced rows is a uniform shift SSP self-corrects.
// fp16 cost matrix in d_ws (2 MB/batch, XCD-L2 resident); FINAL SUM
// recomputed in fp32 from coords.

#define N     1024
#define BATCH 8
#define NSLOT 16          // columns per lane
#define INFV  1e9f
#define QN    2048        // ARR worklist capacity
#define ARR_CAP (6 * N)   // global ARR iteration cap (SSP catches leftovers)

__global__ void emd_zero_kernel(float* out) { out[0] = 0.0f; }

// ---- cost cache: D[b][r][c] = fp16(dist(S1[b][r], S2[b][c])) ----
__global__ __launch_bounds__(256)
void emd_dist_kernel(const float* __restrict__ S1, const float* __restrict__ S2,
                     __half* __restrict__ D) {
    int b = blockIdx.x >> 10;
    int r = blockIdx.x & (N - 1);
    const float* s1 = S1 + ((size_t)b * N + r) * 3;
    float x1 = s1[0], y1 = s1[1], z1 = s1[2];
    const float* s2 = S2 + (size_t)b * N * 3;
    __half* drow = D + ((size_t)b * N + r) * (size_t)N;
    for (int c = threadIdx.x; c < N; c += 256) {
        float dx = x1 - s2[3 * c], dy = y1 - s2[3 * c + 1], dz = z1 - s2[3 * c + 2];
        drow[c] = __float2half_rn(sqrtf(dx * dx + dy * dy + dz * dz));
    }
}

// ---- column reduction over the fp16 matrix: v[c] = min_r C'(r,c) ----
__global__ __launch_bounds__(256)
void emd_colmin_kernel(const __half* __restrict__ D, float* __restrict__ V,
                       int* __restrict__ I) {
    int b = blockIdx.x >> 2;
    int c = ((blockIdx.x & 3) << 8) + threadIdx.x;
    const __half* Db = D + ((size_t)b << 20);
    float best = INFV; int bi = 1;
    for (int r = 0; r < N; ++r) {
        float d = __half2float(Db[(size_t)r * N + c]);
        if (d < best) { best = d; bi = r + 1; }
    }
    V[b * N + c] = best;
    I[b * N + c] = bi;
}

template<int CTRL>
__device__ __forceinline__ float dppmin(float x) {
    int xi = __float_as_int(x);
    int yi = __builtin_amdgcn_update_dpp(xi, xi, CTRL, 0xF, 0xF, false);
    return fminf(x, __int_as_float(yi));
}

__device__ __forceinline__ float wave_min_f32(float x) {
    x = dppmin<0x111>(x);   // row_shr:1
    x = dppmin<0x112>(x);   // row_shr:2
    x = dppmin<0x114>(x);   // row_shr:4
    x = dppmin<0x118>(x);   // row_shr:8
    x = dppmin<0x142>(x);   // row_bcast:15
    x = dppmin<0x143>(x);   // row_bcast:31 -> lane 63 has global min
    return __int_as_float(__builtin_amdgcn_readlane(__float_as_int(x), 63));
}

// ---- ARR kernel: greedy + reduction transfer + augmenting row reduction ----
// One wave per batch. Own register budget; SSP kernel untouched.
__global__ __launch_bounds__(64, 1)
void emd_arr_kernel(const __half* __restrict__ Dc,
                    const float* __restrict__ Vin, const int* __restrict__ Iin,
                    float* __restrict__ Vw, float* __restrict__ Uw,
                    int* __restrict__ Cw, int* __restrict__ Rw) {
    __shared__ int   rowm[N + 1];     // row -> matched col (0 = free)
    __shared__ int   cnt[N + 1];      // # columns whose argmin row is r
    __shared__ float u_lds[N + 1];    // row potentials
    __shared__ int   qbuf[QN];        // free-row worklist

    const int lane = threadIdx.x;
    const int b = blockIdx.x;
    const __half* Db = Dc + ((size_t)b << 20);

    float v[NSLOT]; int pr[NSLOT]; int imin[NSLOT];
#pragma unroll
    for (int k = 0; k < NSLOT; ++k) {
        int c = lane * NSLOT + k;
        v[k] = Vin[b * N + c];
        imin[k] = Iin[b * N + c];
    }
    for (int t = lane; t <= N; t += 64) { rowm[t] = 0; cnt[t] = 0; u_lds[t] = 0.0f; }
    __syncthreads();

    // greedy matching on tight edges (+ match counts for RT)
#pragma unroll
    for (int k = 0; k < NSLOT; ++k) {
        int j = lane * NSLOT + k + 1;
        int r = imin[k];
        atomicAdd(&cnt[r], 1);
        int old = atomicCAS(&rowm[r], 0, j);
        pr[k] = (old == 0) ? r : 0;
    }
    __syncthreads();

    // reduced-cost row: red[k] = C'(rr, col_k) - v[col_k]
    auto rowRed = [&](int rr, float (&red)[NSLOT]) {
        const uint4* dr = (const uint4*)(Db + (size_t)(rr - 1) * N);
        uint4 w0 = dr[lane * 2 + 0];
        uint4 w1 = dr[lane * 2 + 1];
        unsigned wb[8] = { w0.x, w0.y, w0.z, w0.w, w1.x, w1.y, w1.z, w1.w };
#pragma unroll
        for (int t = 0; t < 8; ++t) {
            __half2 hh = *reinterpret_cast<const __half2*>(&wb[t]);
            float2 f2 = __half22float2(hh);
            red[2 * t]     = f2.x - v[2 * t];
            red[2 * t + 1] = f2.y - v[2 * t + 1];
        }
    };
    auto colRowOf = [&](int j) -> int {       // colsol[j] via register pr
        int cc = j - 1, lo = cc >> 4, kk = cc & 15;
        int ploc = pr[0];
#pragma unroll
        for (int k = 1; k < NSLOT; ++k) if (k == kk) ploc = pr[k];
        return __builtin_amdgcn_readlane(ploc, lo);
    };
    auto assignCol = [&](int j, int row) {    // colsol[j] = row
        int cc = j - 1, lo = cc >> 4, kk = cc & 15;
        bool mine = (lane == lo);
#pragma unroll
        for (int k = 0; k < NSLOT; ++k)
            if (k == kk && mine) pr[k] = row;
    };
    auto addV = [&](int j, float d) {         // v[j] += d
        int cc = j - 1, lo = cc >> 4, kk = cc & 15;
        bool mine = (lane == lo);
#pragma unroll
        for (int k = 0; k < NSLOT; ++k)
            if (k == kk && mine) v[k] += d;
    };

    // ---- REDUCTION TRANSFER (rows matched by exactly one column) ----
    for (int i = 1; i <= N; ++i) {
        int j1 = rowm[i];
        if (j1 == 0 || cnt[i] != 1) continue;
        float red[NSLOT];
        rowRed(i, red);
        {   // mask out the matched column
            int cc = j1 - 1, lo = cc >> 4, kk = cc & 15;
            bool mine = (lane == lo);
#pragma unroll
            for (int k = 0; k < NSLOT; ++k)
                if (k == kk && mine) red[k] = INFV;
        }
        // destructive tree min on red (no extra array -> low pressure)
#pragma unroll
        for (int s = 1; s < NSLOT; s <<= 1) {
#pragma unroll
            for (int k = 0; k < NSLOT; k += 2 * s)
                red[k] = fminf(red[k], red[k + s]);
        }
        float m = wave_min_f32(red[0]);
        if (m > 0.0f) {
            addV(j1, -m);
            if (lane == 0) u_lds[i] = m;
        }
    }
    __syncthreads();

    // ---- build free-row worklist (deterministic order) ----
    int tail = 0;
    for (int b0 = 1; b0 <= N; b0 += 64) {
        int i = b0 + lane;
        bool fr = (i <= N) && (rowm[i] == 0);
        unsigned long long mb = __ballot(fr);
        int pre = __popcll(mb & ((1ull << lane) - 1ull));
        if (fr) qbuf[tail + pre] = i;
        tail += (int)__popcll(mb);
    }

    // ---- AUGMENTING ROW REDUCTION (2 passes, JV-style; R9 semantics) ----
    // Reductions rewritten: local depth-16 chain -> 4 depth-4 chains +
    // pair merges; wave butterfly (ds_permute, ~1us) -> DPP wave_min
    // argmin-with-payload. All comparison outcomes preserved => output
    // state bit-identical to R9's.
    {
        int head = 0, pending = 0, iter = 0;
        for (int pass = 0; pass < 2; ++pass) {
            int pend = tail;
            while ((head < pend || pending) && ++iter <= ARR_CAP) {
                int i;
                if (pending) { i = pending; pending = 0; }
                else i = qbuf[head++];

                float red[NSLOT];
                rowRed(i, red);
                // local (min, secmin, argmin-col): 4 chains of depth 4.
                // Contiguous k-blocks; within-chain serial order = old order.
                float a1 = INFV, a2 = INFV; int ac = 0;
                float e1 = INFV, e2 = INFV; int ec = 0;
                float f1 = INFV, f2 = INFV; int fc = 0;
                float g1 = INFV, g2 = INFV; int gc = 0;
#pragma unroll
                for (int k = 0; k < 4; ++k) {
                    float v0 = red[k];
                    bool t0 = v0 < a1;
                    a2 = t0 ? a1 : (v0 < a2 ? v0 : a2);
                    ac = t0 ? (lane * NSLOT + k + 1) : ac;
                    a1 = t0 ? v0 : a1;
                    float v1 = red[k + 4];
                    bool t1 = v1 < e1;
                    e2 = t1 ? e1 : (v1 < e2 ? v1 : e2);
                    ec = t1 ? (lane * NSLOT + k + 5) : ec;
                    e1 = t1 ? v1 : e1;
                    float v2 = red[k + 8];
                    bool t2 = v2 < f1;
                    f2 = t2 ? f1 : (v2 < f2 ? v2 : f2);
                    fc = t2 ? (lane * NSLOT + k + 9) : fc;
                    f1 = t2 ? v2 : f1;
                    float v3 = red[k + 12];
                    bool t3 = v3 < g1;
                    g2 = t3 ? g1 : (v3 < g2 ? v3 : g2);
                    gc = t3 ? (lane * NSLOT + k + 13) : gc;
                    g1 = t3 ? v3 : g1;
                }
                // pair merges; strict '<' on the later block => earlier
                // (lower-col) block wins ties, matching the serial chain.
                bool sae = e1 < a1;
                float ae1 = sae ? e1 : a1; int aec = sae ? ec : ac;
                float ae2 = fminf(fminf(a2, e2), sae ? a1 : e1);
                bool sfg = g1 < f1;
                float fg1 = sfg ? g1 : f1; int fgc = sfg ? gc : fc;
                float fg2 = fminf(fminf(f2, g2), sfg ? f1 : g1);
                bool sall = fg1 < ae1;
                float m1 = sall ? fg1 : ae1;
                int   c1 = sall ? fgc : aec;
                float m2 = fminf(fminf(ae2, fg2), sall ? ae1 : fg1);

                // wave argmin with payload: DPP wave_min + first-winner-lane.
                // Lowest winning lane == lowest tied column (cols lane-major;
                // within-lane c1 already lowest-k) — same tie-break as the
                // old butterfly. gm2 is the exact global second-min.
                float gm1 = wave_min_f32(m1);
                unsigned long long wbm = __ballot(m1 == gm1);
                int wl = __ffsll((long long)wbm) - 1;
                float cand2 = (lane == wl) ? m2 : m1;
                float gm2 = wave_min_f32(cand2);
                int gc1 = __builtin_amdgcn_readlane(c1, wl);
                m1 = gm1; m2 = gm2;
                int j1 = gc1;

                bool strict = m1 < m2;
                int i0 = colRowOf(j1);
                bool doassign = true;
                if (strict) {
                    addV(j1, -(m2 - m1));      // j1's reduced cost -> m2
                } else if (i0 != 0) {
                    // tie & j1 occupied: pick another tie column, prefer FREE
                    unsigned mskA = 0u, mskF = 0u;
#pragma unroll
                    for (int k = 0; k < NSLOT; ++k) {
                        bool tie = (red[k] == m1);
                        mskA |= tie ? (1u << k) : 0u;
                        mskF |= (tie && pr[k] == 0) ? (1u << k) : 0u;
                    }
                    if (lane == ((j1 - 1) >> 4)) {
                        unsigned drop = ~(1u << ((j1 - 1) & 15));
                        mskA &= drop; mskF &= drop;
                    }
                    unsigned long long lmF = __ballot(mskF != 0u);
                    unsigned long long lmA = __ballot(mskA != 0u);
                    unsigned long long lm = lmF ? lmF : lmA;
                    unsigned pickF = lmF ? 1u : 0u;
                    if (lm != 0ull) {
                        int l = __ffsll((long long)lm) - 1;
                        unsigned mk = (unsigned)__builtin_amdgcn_readlane(
                            (int)(pickF ? mskF : mskA), l);
                        int k2 = __ffs((int)mk) - 1;
                        j1 = l * NSLOT + k2 + 1;
                        i0 = colRowOf(j1);
                    } else {
                        doassign = false;       // defensive: row stays free
                    }
                }
                if (doassign) {
                    assignCol(j1, i);
                    if (lane == 0) {
                        rowm[i] = j1;
                        u_lds[i] = m2;          // == m1 in tie case
                        if (i0 != 0) rowm[i0] = 0;
                    }
                    if (i0 != 0) {
                        if (strict) pending = i0;              // JV free[--k]
                        else if (tail < QN) qbuf[tail++] = i0; // next pass
                    }
                }
            }
            if (iter > ARR_CAP) break;
            head = pend;
        }
    }
    __syncthreads();

    // ---- write state for the SSP kernel ----
    for (int t = lane; t < N; t += 64) {
        Rw[b * N + t] = rowm[t + 1];
        Uw[b * N + t] = u_lds[t + 1];
    }
#pragma unroll
    for (int k = 0; k < NSLOT; ++k) {
        int c = lane * NSLOT + k;
        Vw[b * N + c] = v[k];
        Cw[b * N + c] = pr[k];
    }
}

struct Frag { uint4 w0, w1; float ur; float4 q; };

template<bool CACHED, bool PRE>
__global__ __launch_bounds__(64, 1)
void emd_jv_kernel(const float* __restrict__ S1,
                   const float* __restrict__ S2,
                   const __half* __restrict__ Dc,
                   const float* __restrict__ Vin,
                   const int*   __restrict__ Iin,
                   const float* __restrict__ Uw,
                   const int*   __restrict__ Cw,
                   const int*   __restrict__ Rw,
                   float* __restrict__ out) {
    __shared__ float4 s1u[N + 1];     // row coords (both modes; final fp32 sum)
    __shared__ float  u_lds[N + 1];   // row potentials
    __shared__ float  dentry[N + 1];  // D value when column settled
    __shared__ int    rowm[N + 1];    // row -> matched col (0 = free)

    const int lane = threadIdx.x;
    const int b = blockIdx.x;
    const float* s1g = S1 + (size_t)b * N * 3;
    const float* s2g = S2 + (size_t)b * N * 3;
    const __half* Db = CACHED ? (Dc + ((size_t)b << 20)) : (const __half*)0;
    const float NANF = __int_as_float(0x7fc00000);

    for (int t = lane; t < N; t += 64) {
        s1u[t + 1] = make_float4(s1g[3 * t], s1g[3 * t + 1], s1g[3 * t + 2], 0.0f);
        u_lds[t + 1] = PRE ? Uw[b * N + t] : 0.0f;
        rowm[t + 1] = PRE ? Rw[b * N + t] : 0;
    }
    if (lane == 0) { u_lds[0] = 0.0f; rowm[0] = 0; }

    // ---- per-lane column state: col j = c+1, c = lane*16+k ----
    float v[NSLOT];       // column potentials
    int   pr[NSLOT];      // matched row (0 = free)
    int   jpk[NSLOT];     // packed (pr<<11)|j
    float x2[NSLOT], y2[NSLOT], z2[NSLOT];  // S2 coords (final fp32 sum)

#pragma unroll
    for (int k = 0; k < NSLOT; ++k) {
        int pt = lane * NSLOT + k;
        x2[k] = s2g[3 * pt + 0];
        y2[k] = s2g[3 * pt + 1];
        z2[k] = s2g[3 * pt + 2];
    }

    if constexpr (PRE) {
#pragma unroll
        for (int k = 0; k < NSLOT; ++k) {
            int c = lane * NSLOT + k;
            v[k] = Vin[b * N + c];        // Vin = ARR-updated v
            pr[k] = Cw[b * N + c];
            jpk[k] = (pr[k] << 11) | (c + 1);
        }
        __syncthreads();
    } else {
        int imin[NSLOT];
        if constexpr (CACHED) {
#pragma unroll
            for (int k = 0; k < NSLOT; ++k) {
                int c = lane * NSLOT + k;
                v[k] = Vin[b * N + c];
                imin[k] = Iin[b * N + c];
            }
        } else {
#pragma unroll
            for (int k = 0; k < NSLOT; ++k) { v[k] = INFV; imin[k] = 1; }
        }
        __syncthreads();

        if constexpr (!CACHED) {
            for (int r = 1; r <= N; ++r) {
                float4 qq = s1u[r];
#pragma unroll
                for (int k = 0; k < NSLOT; ++k) {
                    float dx = qq.x - x2[k], dy = qq.y - y2[k], dz = qq.z - z2[k];
                    float d2 = dx * dx + dy * dy + dz * dz;
                    bool upd = d2 < v[k];
                    v[k] = upd ? d2 : v[k];
                    imin[k] = upd ? r : imin[k];
                }
            }
#pragma unroll
            for (int k = 0; k < NSLOT; ++k) v[k] = sqrtf(v[k]);
        }

        // greedy matching on tight edges
#pragma unroll
        for (int k = 0; k < NSLOT; ++k) {
            int j = lane * NSLOT + k + 1;
            int r = imin[k];
            int old = atomicCAS(&rowm[r], 0, j);
            pr[k] = (old == 0) ? r : 0;
            jpk[k] = (pr[k] << 11) | j;
        }
        __syncthreads();
    }

    float minv[NSLOT];
    int   way[NSLOT];

    // issue row-r loads (cost-row fragment + u[r]); consumer waits only these
    auto issueLoads = [&](int rr) -> Frag {
        Frag F;
        if (CACHED) {
            const uint4* dr = (const uint4*)(Db + (size_t)(rr - 1) * N);
            F.w0 = dr[lane * 2 + 0];       // 8 halves
            F.w1 = dr[lane * 2 + 1];       // 8 halves
        } else {
            F.q = s1u[rr];
        }
        F.ur = u_lds[rr];
        return F;
    };

    auto applyFrag = [&](const Frag& F, int jpred, float Dh) {
        float base = Dh - F.ur;
        if (CACHED) {
            float h[NSLOT];
            const unsigned* w = (const unsigned*)&F.w0;   // w0,w1 contiguous
#pragma unroll
            for (int t = 0; t < 8; ++t) {
                unsigned word = w[t];
                __half2 hh = *reinterpret_cast<const __half2*>(&word);
                float2 f2 = __half22float2(hh);
                h[2 * t] = f2.x; h[2 * t + 1] = f2.y;
            }
#pragma unroll
            for (int k = 0; k < NSLOT; ++k) {
                float cur = (h[k] - v[k]) + base;
                bool upd = cur < minv[k];         // false for NaN (settled)
                minv[k] = upd ? cur : minv[k];
                way[k] = upd ? jpred : way[k];
            }
        } else {
#pragma unroll
            for (int k = 0; k < NSLOT; ++k) {
                float dx = F.q.x - x2[k], dy = F.q.y - y2[k], dz = F.q.z - z2[k];
                float d = sqrtf(dx * dx + dy * dy + dz * dz);
                float cur = (d - v[k]) + base;
                bool upd = cur < minv[k];
                minv[k] = upd ? cur : minv[k];
                way[k] = upd ? jpred : way[k];
            }
        }
    };

    // ---- successive shortest paths for free rows (exact on C') ----
    for (int i = 1; i <= N; ++i) {
        if (rowm[i] != 0) continue;

        unsigned used = 0u;
        float DT = 0.0f;
        int freecol = 0;
        int pred = 0;      // speculative prefetch: predicted next winner row
        Frag P;            // only read when pred != 0 (assigned then)

        Frag F0 = issueLoads(i);          // overlaps minv/way init
#pragma unroll
        for (int k = 0; k < NSLOT; ++k) { minv[k] = INFV; way[k] = 0; }
        applyFrag(F0, 0, 0.0f);

        int guard = 0;
        for (;;) {
            if (++guard > N + 4) break;
            // local argmin: 4 independent depth-4 chains + 2-level merge.
            float b0 = INFV, b1 = INFV, b2 = INFV, b3 = INFV;
            int   p0 = 0, p1 = 0, p2 = 0, p3 = 0;
#pragma unroll
            for (int k = 0; k < 4; ++k) {
                bool t0 = minv[k]      < b0;
                b0 = t0 ? minv[k]      : b0;  p0 = t0 ? jpk[k]      : p0;
                bool t1 = minv[k + 4]  < b1;
                b1 = t1 ? minv[k + 4]  : b1;  p1 = t1 ? jpk[k + 4]  : p1;
                bool t2 = minv[k + 8]  < b2;
                b2 = t2 ? minv[k + 8]  : b2;  p2 = t2 ? jpk[k + 8]  : p2;
                bool t3 = minv[k + 12] < b3;
                b3 = t3 ? minv[k + 12] : b3;  p3 = t3 ? jpk[k + 12] : p3;
            }
            bool m01 = b1 < b0;  float ba = m01 ? b1 : b0;  int pa = m01 ? p1 : p0;
            bool m23 = b3 < b2;  float bb = m23 ? b3 : b2;  int pb = m23 ? p3 : p2;
            bool mab = bb < ba;  float bestv = mab ? bb : ba;
            int bestjp = mab ? pb : pa;

            float gmin = wave_min_f32(bestv);
            if (!(gmin < INFV * 0.5f)) break;
            unsigned long long tm = __ballot(bestv == gmin);
            DT = gmin;
            freecol = 0;

            // 1) free-column short-circuit: zero expands if any tie is free
            {
                unsigned long long tf = tm;
                while (tf) {
                    int l = __ffsll((long long)tf) - 1;
                    tf &= tf - 1;
                    int jp = __builtin_amdgcn_readlane(bestjp, l);
                    if ((jp >> 11) == 0) { freecol = jp & 0x7FF; break; }
                }
            }
            if (freecol) break;

            // 2) settle all matched ties at gmin
            bool first = true;
            while (tm) {
                int l = __ffsll((long long)tm) - 1;
                tm &= tm - 1;
                int jp = __builtin_amdgcn_readlane(bestjp, l);
                int jj = jp & 0x7FF, rr = jp >> 11;
                Frag F;
                if (CACHED && first && pred != 0 && rr == pred) {
                    F = P;                         // prefetch hit: data resident
                } else {
                    F = issueLoads(rr);            // loads fly during marking
                }
                if (CACHED && first) {
                    // runner-up prefetch for the NEXT round; the wave-min +
                    // ballot here hides under the winner's L2 load latency.
                    float ru = (bestv == gmin) ? INFV : bestv;
                    float rmin = wave_min_f32(ru);
                    pred = 0;
                    if (rmin < INFV * 0.5f) {
                        unsigned long long rb = __ballot(ru == rmin);
                        int rl = __ffsll((long long)rb) - 1;
                        int rjp = __builtin_amdgcn_readlane(bestjp, rl);
                        int prr = rjp >> 11;
                        if (prr != 0) { pred = prr; P = issueLoads(prr); }
                    }
                }
                first = false;
                if (lane == 0) dentry[jj] = gmin;
                int cc = jj - 1, lo = cc >> 4, kk = cc & 15;
                bool mine = (lane == lo);
#pragma unroll
                for (int k = 0; k < NSLOT; ++k)
                    if (k == kk && mine) { minv[k] = NANF; used |= (1u << k); }
                applyFrag(F, jj, gmin);
            }
        }
        if (freecol == 0) continue;

        // deferred dual updates (pre-augment pr)
        if (lane == 0) u_lds[i] += DT;
#pragma unroll
        for (int k = 0; k < NSLOT; ++k) {
            if ((used >> k) & 1u) {
                int j = lane * NSLOT + k + 1;
                float dd = DT - dentry[j];
                v[k] -= dd;
                u_lds[pr[k]] += dd;      // distinct rows: race-free
            }
        }
        __syncthreads();

        // augment along alternating path (register p via readlanes)
        int j0 = freecol;
        int aguard = 0;
        while (j0 != 0) {
            if (++aguard > N + 4) break;
            int cc = j0 - 1;
            int lo = cc >> 4, kk = cc & 15;
            int wloc = way[0];
#pragma unroll
            for (int k = 1; k < NSLOT; ++k) if (k == kk) wloc = way[k];
            int j1 = __builtin_amdgcn_readlane(wloc, lo);
            int np;
            if (j1 == 0) np = i;
            else {
                int c1 = j1 - 1;
                int lo1 = c1 >> 4, kk1 = c1 & 15;
                int ploc = pr[0];
#pragma unroll
                for (int k = 1; k < NSLOT; ++k) if (k == kk1) ploc = pr[k];
                np = __builtin_amdgcn_readlane(ploc, lo1);
            }
            bool mine = (lane == lo);
#pragma unroll
            for (int k = 0; k < NSLOT; ++k)
                if (k == kk) {
                    if (mine) { pr[k] = np; jpk[k] = (np << 11) | j0; }
                }
            if (lane == 0) rowm[np] = j0;
            j0 = j1;
        }
        __syncthreads();
    }

    // ---- total matched cost: exact fp32 from coordinates ----
    float sum = 0.0f;
#pragma unroll
    for (int k = 0; k < NSLOT; ++k) {
        int r = pr[k] > 0 ? pr[k] : 1;
        float4 qq = s1u[r];
        float dx = qq.x - x2[k], dy = qq.y - y2[k], dz = qq.z - z2[k];
        sum += sqrtf(dx * dx + dy * dy + dz * dz);
    }
#pragma unroll
    for (int off = 32; off >= 1; off >>= 1) sum += __shfl_xor(sum, off);
    if (lane == 0) atomicAdd(out, sum * (1.0f / ((float)N * (float)BATCH)));
}

extern "C" void kernel_launch(void* const* d_in, const int* in_sizes, int n_in,
                              void* d_out, int out_size, void* d_ws, size_t ws_size,
                              hipStream_t stream) {
    const float* S1 = (const float*)d_in[0];
    const float* S2 = (const float*)d_in[1];
    float* out = (float*)d_out;

    size_t needD  = (size_t)BATCH * N * N * sizeof(__half);
    size_t vecB   = (size_t)BATCH * N * 4;            // one per-col/per-row array
    size_t needT  = needD + 2 * vecB;                 // V + I            (R8 tier)
    size_t needT2 = needD + 6 * vecB;                 // + Vw,Uw,Cw,Rw    (R9 tier)

    emd_zero_kernel<<<1, 1, 0, stream>>>(out);

    if (ws_size >= needT2) {
        __half* D  = (__half*)d_ws;
        float*  V  = (float*)((char*)d_ws + needD);
        int*    I  = (int*)((char*)V + vecB);
        float*  Vw = (float*)((char*)I + vecB);
        float*  Uw = (float*)((char*)Vw + vecB);
        int*    Cw = (int*)((char*)Uw + vecB);
        int*    Rw = (int*)((char*)Cw + vecB);
        emd_dist_kernel<<<BATCH * N, 256, 0, stream>>>(S1, S2, D);
        emd_colmin_kernel<<<BATCH * 4, 256, 0, stream>>>(D, V, I);
        emd_arr_kernel<<<BATCH, 64, 0, stream>>>(D, V, I, Vw, Uw, Cw, Rw);
        emd_jv_kernel<true, true><<<BATCH, 64, 0, stream>>>(
            S1, S2, D, Vw, nullptr, Uw, Cw, Rw, out);
    } else if (ws_size >= needT) {
        __half* D = (__half*)d_ws;
        float*  V = (float*)((char*)d_ws + needD);
        int*    I = (int*)((char*)V + vecB);
        emd_dist_kernel<<<BATCH * N, 256, 0, stream>>>(S1, S2, D);
        emd_colmin_kernel<<<BATCH * 4, 256, 0, stream>>>(D, V, I);
        emd_jv_kernel<true, false><<<BATCH, 64, 0, stream>>>(
            S1, S2, D, V, I, nullptr, nullptr, nullptr, out);
    } else {
        emd_jv_kernel<false, false><<<BATCH, 64, 0, stream>>>(
            S1, S2, nullptr, nullptr, nullptr, nullptr, nullptr, nullptr, out);
    }
}

// Round 6
// 23607.646 us; speedup vs baseline: 1.1469x; 1.1469x over previous
//
#include <hip/hip_runtime.h>
#include <hip/hip_fp16.h>
#include <math.h>

// EarthMoverDistance: exact Hungarian (JV successive shortest path).
// B=8, N=1024, 3-D Euclidean cost. One wave per batch; lane owns 16 columns
// (c = lane*16+k) in registers.
// R12 (base = R11, 27.1 ms = 18.88 jv + ~7.6 arr + ~0.6 pre):
//  - ONLY the ARR kernel changes (single-variable round; jv byte-identical):
//    (a) cap = 2*tail + 64 (was 6144): R11 ran to the cap because
//        tie-displacement ping-pong (no addV, net-zero matching) churns;
//        productive work (strict dual-tightening, net row resolution) is
//        front-loaded. Truncation at any point preserves the invariants.
//    (b) next-row prefetch: after resolving the current row fragment,
//        issue qbuf[head]'s raw cost-row loads; non-displacing iterations
//        (the common case) find next iter's data resident. Raw halves
//        cached; red = raw - v recomputed with current v (never stale).
//  - R11 post-mortem: DPP argmin preserved R9 state exactly (jv back to
//    18.88); remaining 1.2us/iter = serialized L2 row-load round-trip.
// Invariants (R7/R9/R11, absmax 0.0): duals only tighten, matched edges
// tight; stale u on displaced rows is a uniform shift SSP self-corrects.
// fp16 cost matrix in d_ws (2 MB/batch, XCD-L2 resident); FINAL SUM
// recomputed in fp32 from coords.

#define N     1024
#define BATCH 8
#define NSLOT 16          // columns per lane
#define INFV  1e9f
#define QN    2048        // ARR worklist capacity

__global__ void emd_zero_kernel(float* out) { out[0] = 0.0f; }

// ---- cost cache: D[b][r][c] = fp16(dist(S1[b][r], S2[b][c])) ----
__global__ __launch_bounds__(256)
void emd_dist_kernel(const float* __restrict__ S1, const float* __restrict__ S2,
                     __half* __restrict__ D) {
    int b = blockIdx.x >> 10;
    int r = blockIdx.x & (N - 1);
    const float* s1 = S1 + ((size_t)b * N + r) * 3;
    float x1 = s1[0], y1 = s1[1], z1 = s1[2];
    const float* s2 = S2 + (size_t)b * N * 3;
    __half* drow = D + ((size_t)b * N + r) * (size_t)N;
    for (int c = threadIdx.x; c < N; c += 256) {
        float dx = x1 - s2[3 * c], dy = y1 - s2[3 * c + 1], dz = z1 - s2[3 * c + 2];
        drow[c] = __float2half_rn(sqrtf(dx * dx + dy * dy + dz * dz));
    }
}

// ---- column reduction over the fp16 matrix: v[c] = min_r C'(r,c) ----
__global__ __launch_bounds__(256)
void emd_colmin_kernel(const __half* __restrict__ D, float* __restrict__ V,
                       int* __restrict__ I) {
    int b = blockIdx.x >> 2;
    int c = ((blockIdx.x & 3) << 8) + threadIdx.x;
    const __half* Db = D + ((size_t)b << 20);
    float best = INFV; int bi = 1;
    for (int r = 0; r < N; ++r) {
        float d = __half2float(Db[(size_t)r * N + c]);
        if (d < best) { best = d; bi = r + 1; }
    }
    V[b * N + c] = best;
    I[b * N + c] = bi;
}

template<int CTRL>
__device__ __forceinline__ float dppmin(float x) {
    int xi = __float_as_int(x);
    int yi = __builtin_amdgcn_update_dpp(xi, xi, CTRL, 0xF, 0xF, false);
    return fminf(x, __int_as_float(yi));
}

__device__ __forceinline__ float wave_min_f32(float x) {
    x = dppmin<0x111>(x);   // row_shr:1
    x = dppmin<0x112>(x);   // row_shr:2
    x = dppmin<0x114>(x);   // row_shr:4
    x = dppmin<0x118>(x);   // row_shr:8
    x = dppmin<0x142>(x);   // row_bcast:15
    x = dppmin<0x143>(x);   // row_bcast:31 -> lane 63 has global min
    return __int_as_float(__builtin_amdgcn_readlane(__float_as_int(x), 63));
}

// ---- ARR kernel: greedy + reduction transfer + augmenting row reduction ----
// One wave per batch. Own register budget; SSP kernel untouched.
__global__ __launch_bounds__(64, 1)
void emd_arr_kernel(const __half* __restrict__ Dc,
                    const float* __restrict__ Vin, const int* __restrict__ Iin,
                    float* __restrict__ Vw, float* __restrict__ Uw,
                    int* __restrict__ Cw, int* __restrict__ Rw) {
    __shared__ int   rowm[N + 1];     // row -> matched col (0 = free)
    __shared__ int   cnt[N + 1];      // # columns whose argmin row is r
    __shared__ float u_lds[N + 1];    // row potentials
    __shared__ int   qbuf[QN];        // free-row worklist

    const int lane = threadIdx.x;
    const int b = blockIdx.x;
    const __half* Db = Dc + ((size_t)b << 20);

    float v[NSLOT]; int pr[NSLOT]; int imin[NSLOT];
#pragma unroll
    for (int k = 0; k < NSLOT; ++k) {
        int c = lane * NSLOT + k;
        v[k] = Vin[b * N + c];
        imin[k] = Iin[b * N + c];
    }
    for (int t = lane; t <= N; t += 64) { rowm[t] = 0; cnt[t] = 0; u_lds[t] = 0.0f; }
    __syncthreads();

    // greedy matching on tight edges (+ match counts for RT)
#pragma unroll
    for (int k = 0; k < NSLOT; ++k) {
        int j = lane * NSLOT + k + 1;
        int r = imin[k];
        atomicAdd(&cnt[r], 1);
        int old = atomicCAS(&rowm[r], 0, j);
        pr[k] = (old == 0) ? r : 0;
    }
    __syncthreads();

    // reduced-cost row: red[k] = C'(rr, col_k) - v[col_k]
    auto rowRed = [&](int rr, float (&red)[NSLOT]) {
        const uint4* dr = (const uint4*)(Db + (size_t)(rr - 1) * N);
        uint4 w0 = dr[lane * 2 + 0];
        uint4 w1 = dr[lane * 2 + 1];
        unsigned wb[8] = { w0.x, w0.y, w0.z, w0.w, w1.x, w1.y, w1.z, w1.w };
#pragma unroll
        for (int t = 0; t < 8; ++t) {
            __half2 hh = *reinterpret_cast<const __half2*>(&wb[t]);
            float2 f2 = __half22float2(hh);
            red[2 * t]     = f2.x - v[2 * t];
            red[2 * t + 1] = f2.y - v[2 * t + 1];
        }
    };
    auto colRowOf = [&](int j) -> int {       // colsol[j] via register pr
        int cc = j - 1, lo = cc >> 4, kk = cc & 15;
        int ploc = pr[0];
#pragma unroll
        for (int k = 1; k < NSLOT; ++k) if (k == kk) ploc = pr[k];
        return __builtin_amdgcn_readlane(ploc, lo);
    };
    auto assignCol = [&](int j, int row) {    // colsol[j] = row
        int cc = j - 1, lo = cc >> 4, kk = cc & 15;
        bool mine = (lane == lo);
#pragma unroll
        for (int k = 0; k < NSLOT; ++k)
            if (k == kk && mine) pr[k] = row;
    };
    auto addV = [&](int j, float d) {         // v[j] += d
        int cc = j - 1, lo = cc >> 4, kk = cc & 15;
        bool mine = (lane == lo);
#pragma unroll
        for (int k = 0; k < NSLOT; ++k)
            if (k == kk && mine) v[k] += d;
    };

    // ---- REDUCTION TRANSFER (rows matched by exactly one column) ----
    for (int i = 1; i <= N; ++i) {
        int j1 = rowm[i];
        if (j1 == 0 || cnt[i] != 1) continue;
        float red[NSLOT];
        rowRed(i, red);
        {   // mask out the matched column
            int cc = j1 - 1, lo = cc >> 4, kk = cc & 15;
            bool mine = (lane == lo);
#pragma unroll
            for (int k = 0; k < NSLOT; ++k)
                if (k == kk && mine) red[k] = INFV;
        }
        // destructive tree min on red (no extra array -> low pressure)
#pragma unroll
        for (int s = 1; s < NSLOT; s <<= 1) {
#pragma unroll
            for (int k = 0; k < NSLOT; k += 2 * s)
                red[k] = fminf(red[k], red[k + s]);
        }
        float m = wave_min_f32(red[0]);
        if (m > 0.0f) {
            addV(j1, -m);
            if (lane == 0) u_lds[i] = m;
        }
    }
    __syncthreads();

    // ---- build free-row worklist (deterministic order) ----
    int tail = 0;
    for (int b0 = 1; b0 <= N; b0 += 64) {
        int i = b0 + lane;
        bool fr = (i <= N) && (rowm[i] == 0);
        unsigned long long mb = __ballot(fr);
        int pre = __popcll(mb & ((1ull << lane) - 1ull));
        if (fr) qbuf[tail + pre] = i;
        tail += (int)__popcll(mb);
    }

    // ---- AUGMENTING ROW REDUCTION (2 passes, JV-style; R9 semantics,
    //      truncated churn + next-row prefetch) ----
    {
        // raw next-row prefetch cache (cost matrix is constant -> never stale)
        uint4 pw0, pw1; int pi = 0;
        auto prefRow = [&](int rr) {
            const uint4* dr = (const uint4*)(Db + (size_t)(rr - 1) * N);
            pw0 = dr[lane * 2 + 0];
            pw1 = dr[lane * 2 + 1];
            pi = rr;
        };

        int head = 0, pending = 0, iter = 0;
        const int cap = 2 * tail + 64;   // truncate tie-displacement churn
        for (int pass = 0; pass < 2; ++pass) {
            int pend = tail;
            while ((head < pend || pending) && ++iter <= cap) {
                int i;
                if (pending) { i = pending; pending = 0; }
                else i = qbuf[head++];

                float red[NSLOT];
                if (i == pi) {           // prefetch hit: raw words resident
                    unsigned wb[8] = { pw0.x, pw0.y, pw0.z, pw0.w,
                                       pw1.x, pw1.y, pw1.z, pw1.w };
#pragma unroll
                    for (int t = 0; t < 8; ++t) {
                        __half2 hh = *reinterpret_cast<const __half2*>(&wb[t]);
                        float2 f2 = __half22float2(hh);
                        red[2 * t]     = f2.x - v[2 * t];
                        red[2 * t + 1] = f2.y - v[2 * t + 1];
                    }
                } else {
                    rowRed(i, red);
                }
                // prefetch the next worklist entry; it is the next row
                // whenever this iteration doesn't displace (common case).
                if (head < tail) prefRow(qbuf[head]);

                // local (min, secmin, argmin-col): 4 chains of depth 4.
                float a1 = INFV, a2 = INFV; int ac = 0;
                float e1 = INFV, e2 = INFV; int ec = 0;
                float f1 = INFV, f2 = INFV; int fc = 0;
                float g1 = INFV, g2 = INFV; int gc = 0;
#pragma unroll
                for (int k = 0; k < 4; ++k) {
                    float v0 = red[k];
                    bool t0 = v0 < a1;
                    a2 = t0 ? a1 : (v0 < a2 ? v0 : a2);
                    ac = t0 ? (lane * NSLOT + k + 1) : ac;
                    a1 = t0 ? v0 : a1;
                    float v1 = red[k + 4];
                    bool t1 = v1 < e1;
                    e2 = t1 ? e1 : (v1 < e2 ? v1 : e2);
                    ec = t1 ? (lane * NSLOT + k + 5) : ec;
                    e1 = t1 ? v1 : e1;
                    float v2 = red[k + 8];
                    bool t2 = v2 < f1;
                    f2 = t2 ? f1 : (v2 < f2 ? v2 : f2);
                    fc = t2 ? (lane * NSLOT + k + 9) : fc;
                    f1 = t2 ? v2 : f1;
                    float v3 = red[k + 12];
                    bool t3 = v3 < g1;
                    g2 = t3 ? g1 : (v3 < g2 ? v3 : g2);
                    gc = t3 ? (lane * NSLOT + k + 13) : gc;
                    g1 = t3 ? v3 : g1;
                }
                bool sae = e1 < a1;
                float ae1 = sae ? e1 : a1; int aec = sae ? ec : ac;
                float ae2 = fminf(fminf(a2, e2), sae ? a1 : e1);
                bool sfg = g1 < f1;
                float fg1 = sfg ? g1 : f1; int fgc = sfg ? gc : fc;
                float fg2 = fminf(fminf(f2, g2), sfg ? f1 : g1);
                bool sall = fg1 < ae1;
                float m1 = sall ? fg1 : ae1;
                int   c1 = sall ? fgc : aec;
                float m2 = fminf(fminf(ae2, fg2), sall ? ae1 : fg1);

                // wave argmin with payload: DPP wave_min + first-winner-lane.
                float gm1 = wave_min_f32(m1);
                unsigned long long wbm = __ballot(m1 == gm1);
                int wl = __ffsll((long long)wbm) - 1;
                float cand2 = (lane == wl) ? m2 : m1;
                float gm2 = wave_min_f32(cand2);
                int gc1 = __builtin_amdgcn_readlane(c1, wl);
                m1 = gm1; m2 = gm2;
                int j1 = gc1;

                bool strict = m1 < m2;
                int i0 = colRowOf(j1);
                bool doassign = true;
                if (strict) {
                    addV(j1, -(m2 - m1));      // j1's reduced cost -> m2
                } else if (i0 != 0) {
                    // tie & j1 occupied: pick another tie column, prefer FREE
                    unsigned mskA = 0u, mskF = 0u;
#pragma unroll
                    for (int k = 0; k < NSLOT; ++k) {
                        bool tie = (red[k] == m1);
                        mskA |= tie ? (1u << k) : 0u;
                        mskF |= (tie && pr[k] == 0) ? (1u << k) : 0u;
                    }
                    if (lane == ((j1 - 1) >> 4)) {
                        unsigned drop = ~(1u << ((j1 - 1) & 15));
                        mskA &= drop; mskF &= drop;
                    }
                    unsigned long long lmF = __ballot(mskF != 0u);
                    unsigned long long lmA = __ballot(mskA != 0u);
                    unsigned long long lm = lmF ? lmF : lmA;
                    unsigned pickF = lmF ? 1u : 0u;
                    if (lm != 0ull) {
                        int l = __ffsll((long long)lm) - 1;
                        unsigned mk = (unsigned)__builtin_amdgcn_readlane(
                            (int)(pickF ? mskF : mskA), l);
                        int k2 = __ffs((int)mk) - 1;
                        j1 = l * NSLOT + k2 + 1;
                        i0 = colRowOf(j1);
                    } else {
                        doassign = false;       // defensive: row stays free
                    }
                }
                if (doassign) {
                    assignCol(j1, i);
                    if (lane == 0) {
                        rowm[i] = j1;
                        u_lds[i] = m2;          // == m1 in tie case
                        if (i0 != 0) rowm[i0] = 0;
                    }
                    if (i0 != 0) {
                        if (strict) pending = i0;              // JV free[--k]
                        else if (tail < QN) qbuf[tail++] = i0; // next pass
                    }
                }
            }
            if (iter > cap) break;
            head = pend;
        }
    }
    __syncthreads();

    // ---- write state for the SSP kernel ----
    for (int t = lane; t < N; t += 64) {
        Rw[b * N + t] = rowm[t + 1];
        Uw[b * N + t] = u_lds[t + 1];
    }
#pragma unroll
    for (int k = 0; k < NSLOT; ++k) {
        int c = lane * NSLOT + k;
        Vw[b * N + c] = v[k];
        Cw[b * N + c] = pr[k];
    }
}

struct Frag { uint4 w0, w1; float ur; float4 q; };

template<bool CACHED, bool PRE>
__global__ __launch_bounds__(64, 1)
void emd_jv_kernel(const float* __restrict__ S1,
                   const float* __restrict__ S2,
                   const __half* __restrict__ Dc,
                   const float* __restrict__ Vin,
                   const int*   __restrict__ Iin,
                   const float* __restrict__ Uw,
                   const int*   __restrict__ Cw,
                   const int*   __restrict__ Rw,
                   float* __restrict__ out) {
    __shared__ float4 s1u[N + 1];     // row coords (both modes; final fp32 sum)
    __shared__ float  u_lds[N + 1];   // row potentials
    __shared__ float  dentry[N + 1];  // D value when column settled
    __shared__ int    rowm[N + 1];    // row -> matched col (0 = free)

    const int lane = threadIdx.x;
    const int b = blockIdx.x;
    const float* s1g = S1 + (size_t)b * N * 3;
    const float* s2g = S2 + (size_t)b * N * 3;
    const __half* Db = CACHED ? (Dc + ((size_t)b << 20)) : (const __half*)0;
    const float NANF = __int_as_float(0x7fc00000);

    for (int t = lane; t < N; t += 64) {
        s1u[t + 1] = make_float4(s1g[3 * t], s1g[3 * t + 1], s1g[3 * t + 2], 0.0f);
        u_lds[t + 1] = PRE ? Uw[b * N + t] : 0.0f;
        rowm[t + 1] = PRE ? Rw[b * N + t] : 0;
    }
    if (lane == 0) { u_lds[0] = 0.0f; rowm[0] = 0; }

    // ---- per-lane column state: col j = c+1, c = lane*16+k ----
    float v[NSLOT];       // column potentials
    int   pr[NSLOT];      // matched row (0 = free)
    int   jpk[NSLOT];     // packed (pr<<11)|j
    float x2[NSLOT], y2[NSLOT], z2[NSLOT];  // S2 coords (final fp32 sum)

#pragma unroll
    for (int k = 0; k < NSLOT; ++k) {
        int pt = lane * NSLOT + k;
        x2[k] = s2g[3 * pt + 0];
        y2[k] = s2g[3 * pt + 1];
        z2[k] = s2g[3 * pt + 2];
    }

    if constexpr (PRE) {
#pragma unroll
        for (int k = 0; k < NSLOT; ++k) {
            int c = lane * NSLOT + k;
            v[k] = Vin[b * N + c];        // Vin = ARR-updated v
            pr[k] = Cw[b * N + c];
            jpk[k] = (pr[k] << 11) | (c + 1);
        }
        __syncthreads();
    } else {
        int imin[NSLOT];
        if constexpr (CACHED) {
#pragma unroll
            for (int k = 0; k < NSLOT; ++k) {
                int c = lane * NSLOT + k;
                v[k] = Vin[b * N + c];
                imin[k] = Iin[b * N + c];
            }
        } else {
#pragma unroll
            for (int k = 0; k < NSLOT; ++k) { v[k] = INFV; imin[k] = 1; }
        }
        __syncthreads();

        if constexpr (!CACHED) {
            for (int r = 1; r <= N; ++r) {
                float4 qq = s1u[r];
#pragma unroll
                for (int k = 0; k < NSLOT; ++k) {
                    float dx = qq.x - x2[k], dy = qq.y - y2[k], dz = qq.z - z2[k];
                    float d2 = dx * dx + dy * dy + dz * dz;
                    bool upd = d2 < v[k];
                    v[k] = upd ? d2 : v[k];
                    imin[k] = upd ? r : imin[k];
                }
            }
#pragma unroll
            for (int k = 0; k < NSLOT; ++k) v[k] = sqrtf(v[k]);
        }

        // greedy matching on tight edges
#pragma unroll
        for (int k = 0; k < NSLOT; ++k) {
            int j = lane * NSLOT + k + 1;
            int r = imin[k];
            int old = atomicCAS(&rowm[r], 0, j);
            pr[k] = (old == 0) ? r : 0;
            jpk[k] = (pr[k] << 11) | j;
        }
        __syncthreads();
    }

    float minv[NSLOT];
    int   way[NSLOT];

    // issue row-r loads (cost-row fragment + u[r]); consumer waits only these
    auto issueLoads = [&](int rr) -> Frag {
        Frag F;
        if (CACHED) {
            const uint4* dr = (const uint4*)(Db + (size_t)(rr - 1) * N);
            F.w0 = dr[lane * 2 + 0];       // 8 halves
            F.w1 = dr[lane * 2 + 1];       // 8 halves
        } else {
            F.q = s1u[rr];
        }
        F.ur = u_lds[rr];
        return F;
    };

    auto applyFrag = [&](const Frag& F, int jpred, float Dh) {
        float base = Dh - F.ur;
        if (CACHED) {
            float h[NSLOT];
            const unsigned* w = (const unsigned*)&F.w0;   // w0,w1 contiguous
#pragma unroll
            for (int t = 0; t < 8; ++t) {
                unsigned word = w[t];
                __half2 hh = *reinterpret_cast<const __half2*>(&word);
                float2 f2 = __half22float2(hh);
                h[2 * t] = f2.x; h[2 * t + 1] = f2.y;
            }
#pragma unroll
            for (int k = 0; k < NSLOT; ++k) {
                float cur = (h[k] - v[k]) + base;
                bool upd = cur < minv[k];         // false for NaN (settled)
                minv[k] = upd ? cur : minv[k];
                way[k] = upd ? jpred : way[k];
            }
        } else {
#pragma unroll
            for (int k = 0; k < NSLOT; ++k) {
                float dx = F.q.x - x2[k], dy = F.q.y - y2[k], dz = F.q.z - z2[k];
                float d = sqrtf(dx * dx + dy * dy + dz * dz);
                float cur = (d - v[k]) + base;
                bool upd = cur < minv[k];
                minv[k] = upd ? cur : minv[k];
                way[k] = upd ? jpred : way[k];
            }
        }
    };

    // ---- successive shortest paths for free rows (exact on C') ----
    for (int i = 1; i <= N; ++i) {
        if (rowm[i] != 0) continue;

        unsigned used = 0u;
        float DT = 0.0f;
        int freecol = 0;
        int pred = 0;      // speculative prefetch: predicted next winner row
        Frag P;            // only read when pred != 0 (assigned then)

        Frag F0 = issueLoads(i);          // overlaps minv/way init
#pragma unroll
        for (int k = 0; k < NSLOT; ++k) { minv[k] = INFV; way[k] = 0; }
        applyFrag(F0, 0, 0.0f);

        int guard = 0;
        for (;;) {
            if (++guard > N + 4) break;
            // local argmin: 4 independent depth-4 chains + 2-level merge.
            float b0 = INFV, b1 = INFV, b2 = INFV, b3 = INFV;
            int   p0 = 0, p1 = 0, p2 = 0, p3 = 0;
#pragma unroll
            for (int k = 0; k < 4; ++k) {
                bool t0 = minv[k]      < b0;
                b0 = t0 ? minv[k]      : b0;  p0 = t0 ? jpk[k]      : p0;
                bool t1 = minv[k + 4]  < b1;
                b1 = t1 ? minv[k + 4]  : b1;  p1 = t1 ? jpk[k + 4]  : p1;
                bool t2 = minv[k + 8]  < b2;
                b2 = t2 ? minv[k + 8]  : b2;  p2 = t2 ? jpk[k + 8]  : p2;
                bool t3 = minv[k + 12] < b3;
                b3 = t3 ? minv[k + 12] : b3;  p3 = t3 ? jpk[k + 12] : p3;
            }
            bool m01 = b1 < b0;  float ba = m01 ? b1 : b0;  int pa = m01 ? p1 : p0;
            bool m23 = b3 < b2;  float bb = m23 ? b3 : b2;  int pb = m23 ? p3 : p2;
            bool mab = bb < ba;  float bestv = mab ? bb : ba;
            int bestjp = mab ? pb : pa;

            float gmin = wave_min_f32(bestv);
            if (!(gmin < INFV * 0.5f)) break;
            unsigned long long tm = __ballot(bestv == gmin);
            DT = gmin;
            freecol = 0;

            // 1) free-column short-circuit: zero expands if any tie is free
            {
                unsigned long long tf = tm;
                while (tf) {
                    int l = __ffsll((long long)tf) - 1;
                    tf &= tf - 1;
                    int jp = __builtin_amdgcn_readlane(bestjp, l);
                    if ((jp >> 11) == 0) { freecol = jp & 0x7FF; break; }
                }
            }
            if (freecol) break;

            // 2) settle all matched ties at gmin
            bool first = true;
            while (tm) {
                int l = __ffsll((long long)tm) - 1;
                tm &= tm - 1;
                int jp = __builtin_amdgcn_readlane(bestjp, l);
                int jj = jp & 0x7FF, rr = jp >> 11;
                Frag F;
                if (CACHED && first && pred != 0 && rr == pred) {
                    F = P;                         // prefetch hit: data resident
                } else {
                    F = issueLoads(rr);            // loads fly during marking
                }
                if (CACHED && first) {
                    // runner-up prefetch for the NEXT round; the wave-min +
                    // ballot here hides under the winner's L2 load latency.
                    float ru = (bestv == gmin) ? INFV : bestv;
                    float rmin = wave_min_f32(ru);
                    pred = 0;
                    if (rmin < INFV * 0.5f) {
                        unsigned long long rb = __ballot(ru == rmin);
                        int rl = __ffsll((long long)rb) - 1;
                        int rjp = __builtin_amdgcn_readlane(bestjp, rl);
                        int prr = rjp >> 11;
                        if (prr != 0) { pred = prr; P = issueLoads(prr); }
                    }
                }
                first = false;
                if (lane == 0) dentry[jj] = gmin;
                int cc = jj - 1, lo = cc >> 4, kk = cc & 15;
                bool mine = (lane == lo);
#pragma unroll
                for (int k = 0; k < NSLOT; ++k)
                    if (k == kk && mine) { minv[k] = NANF; used |= (1u << k); }
                applyFrag(F, jj, gmin);
            }
        }
        if (freecol == 0) continue;

        // deferred dual updates (pre-augment pr)
        if (lane == 0) u_lds[i] += DT;
#pragma unroll
        for (int k = 0; k < NSLOT; ++k) {
            if ((used >> k) & 1u) {
                int j = lane * NSLOT + k + 1;
                float dd = DT - dentry[j];
                v[k] -= dd;
                u_lds[pr[k]] += dd;      // distinct rows: race-free
            }
        }
        __syncthreads();

        // augment along alternating path (register p via readlanes)
        int j0 = freecol;
        int aguard = 0;
        while (j0 != 0) {
            if (++aguard > N + 4) break;
            int cc = j0 - 1;
            int lo = cc >> 4, kk = cc & 15;
            int wloc = way[0];
#pragma unroll
            for (int k = 1; k < NSLOT; ++k) if (k == kk) wloc = way[k];
            int j1 = __builtin_amdgcn_readlane(wloc, lo);
            int np;
            if (j1 == 0) np = i;
            else {
                int c1 = j1 - 1;
                int lo1 = c1 >> 4, kk1 = c1 & 15;
                int ploc = pr[0];
#pragma unroll
                for (int k = 1; k < NSLOT; ++k) if (k == kk1) ploc = pr[k];
                np = __builtin_amdgcn_readlane(ploc, lo1);
            }
            bool mine = (lane == lo);
#pragma unroll
            for (int k = 0; k < NSLOT; ++k)
                if (k == kk) {
                    if (mine) { pr[k] = np; jpk[k] = (np << 11) | j0; }
                }
            if (lane == 0) rowm[np] = j0;
            j0 = j1;
        }
        __syncthreads();
    }

    // ---- total matched cost: exact fp32 from coordinates ----
    float sum = 0.0f;
#pragma unroll
    for (int k = 0; k < NSLOT; ++k) {
        int r = pr[k] > 0 ? pr[k] : 1;
        float4 qq = s1u[r];
        float dx = qq.x - x2[k], dy = qq.y - y2[k], dz = qq.z - z2[k];
        sum += sqrtf(dx * dx + dy * dy + dz * dz);
    }
#pragma unroll
    for (int off = 32; off >= 1; off >>= 1) sum += __shfl_xor(sum, off);
    if (lane == 0) atomicAdd(out, sum * (1.0f / ((float)N * (float)BATCH)));
}

extern "C" void kernel_launch(void* const* d_in, const int* in_sizes, int n_in,
                              void* d_out, int out_size, void* d_ws, size_t ws_size,
                              hipStream_t stream) {
    const float* S1 = (const float*)d_in[0];
    const float* S2 = (const float*)d_in[1];
    float* out = (float*)d_out;

    size_t needD  = (size_t)BATCH * N * N * sizeof(__half);
    size_t vecB   = (size_t)BATCH * N * 4;            // one per-col/per-row array
    size_t needT  = needD + 2 * vecB;                 // V + I            (R8 tier)
    size_t needT2 = needD + 6 * vecB;                 // + Vw,Uw,Cw,Rw    (R9 tier)

    emd_zero_kernel<<<1, 1, 0, stream>>>(out);

    if (ws_size >= needT2) {
        __half* D  = (__half*)d_ws;
        float*  V  = (float*)((char*)d_ws + needD);
        int*    I  = (int*)((char*)V + vecB);
        float*  Vw = (float*)((char*)I + vecB);
        float*  Uw = (float*)((char*)Vw + vecB);
        int*    Cw = (int*)((char*)Uw + vecB);
        int*    Rw = (int*)((char*)Cw + vecB);
        emd_dist_kernel<<<BATCH * N, 256, 0, stream>>>(S1, S2, D);
        emd_colmin_kernel<<<BATCH * 4, 256, 0, stream>>>(D, V, I);
        emd_arr_kernel<<<BATCH, 64, 0, stream>>>(D, V, I, Vw, Uw, Cw, Rw);
        emd_jv_kernel<true, true><<<BATCH, 64, 0, stream>>>(
            S1, S2, D, Vw, nullptr, Uw, Cw, Rw, out);
    } else if (ws_size >= needT) {
        __half* D = (__half*)d_ws;
        float*  V = (float*)((char*)d_ws + needD);
        int*    I = (int*)((char*)V + vecB);
        emd_dist_kernel<<<BATCH * N, 256, 0, stream>>>(S1, S2, D);
        emd_colmin_kernel<<<BATCH * 4, 256, 0, stream>>>(D, V, I);
        emd_jv_kernel<true, false><<<BATCH, 64, 0, stream>>>(
            S1, S2, D, V, I, nullptr, nullptr, nullptr, out);
    } else {
        emd_jv_kernel<false, false><<<BATCH, 64, 0, stream>>>(
            S1, S2, nullptr, nullptr, nullptr, nullptr, nullptr, nullptr, out);
    }
}

// Round 7
// 18951.158 us; speedup vs baseline: 1.4287x; 1.2457x over previous
//
#include <hip/hip_runtime.h>
#include <hip/hip_fp16.h>
#include <math.h>

// EarthMoverDistance: exact Hungarian (JV successive shortest path).
// B=8, N=1024, 3-D Euclidean cost. SSP: one wave per batch; lane owns 16
// columns (c = lane*16+k) in registers.
// R13 (base = R12, 23.6 ms):
//  - R12 post-mortem: truncating ARR churn killed its benefit (jv 18.88 ->
//    22.0) => the tie-displacement chains ARE the productive work. A serial
//    one-wave initializer can't be both effective (~6000 iters) and cheap
//    (~1.2us/iter serialized). So: PARALLEL AUCTION initializer instead.
//  - emd_auction_kernel (8 blocks x 1024 threads = 16 waves/batch):
//    per round, ALL free rows bid simultaneously (one wave scans one row:
//    min/secmin/argmin via DPP), columns accept the best bid via 64-bit
//    atomicMax on packed (inc,row), v[j] -= (m2-m1), displaced rows re-bid
//    next round (Jacobi ARR: same displacement dynamics as R11, ~150x
//    cheaper per round). Then parallel u-fixup: u_i = rowmin(C_i - v) for
//    all rows; drop non-tight matches (analysis: v_j frozen while matched,
//    other red only rises => drops ~0). Gives bit-exact SSP feasibility:
//    red >= 0 everywhere, red == 0 on kept matches; u = exact rowmin is
//    tighter than ARR's second-min u.
//  - SSP kernel byte-identical to R12 (prefetch kept); its warm time is
//    the state-quality probe, auction dispatch time the cost probe.
// fp16 cost matrix in d_ws (2 MB/batch, XCD-L2 resident); FINAL SUM
// recomputed in fp32 from coords (absmax 0.0 across R6-R12 variants).

#define N     1024
#define BATCH 8
#define NSLOT 16          // columns per lane (SSP)
#define INFV  1e9f
#define AUC_ROUNDS 24

__global__ void emd_zero_kernel(float* out) { out[0] = 0.0f; }

// ---- cost cache: D[b][r][c] = fp16(dist(S1[b][r], S2[b][c])) ----
__global__ __launch_bounds__(256)
void emd_dist_kernel(const float* __restrict__ S1, const float* __restrict__ S2,
                     __half* __restrict__ D) {
    int b = blockIdx.x >> 10;
    int r = blockIdx.x & (N - 1);
    const float* s1 = S1 + ((size_t)b * N + r) * 3;
    float x1 = s1[0], y1 = s1[1], z1 = s1[2];
    const float* s2 = S2 + (size_t)b * N * 3;
    __half* drow = D + ((size_t)b * N + r) * (size_t)N;
    for (int c = threadIdx.x; c < N; c += 256) {
        float dx = x1 - s2[3 * c], dy = y1 - s2[3 * c + 1], dz = z1 - s2[3 * c + 2];
        drow[c] = __float2half_rn(sqrtf(dx * dx + dy * dy + dz * dz));
    }
}

// ---- column reduction over the fp16 matrix: v[c] = min_r C'(r,c) ----
__global__ __launch_bounds__(256)
void emd_colmin_kernel(const __half* __restrict__ D, float* __restrict__ V,
                       int* __restrict__ I) {
    int b = blockIdx.x >> 2;
    int c = ((blockIdx.x & 3) << 8) + threadIdx.x;
    const __half* Db = D + ((size_t)b << 20);
    float best = INFV; int bi = 1;
    for (int r = 0; r < N; ++r) {
        float d = __half2float(Db[(size_t)r * N + c]);
        if (d < best) { best = d; bi = r + 1; }
    }
    V[b * N + c] = best;
    I[b * N + c] = bi;
}

template<int CTRL>
__device__ __forceinline__ float dppmin(float x) {
    int xi = __float_as_int(x);
    int yi = __builtin_amdgcn_update_dpp(xi, xi, CTRL, 0xF, 0xF, false);
    return fminf(x, __int_as_float(yi));
}

__device__ __forceinline__ float wave_min_f32(float x) {
    x = dppmin<0x111>(x);   // row_shr:1
    x = dppmin<0x112>(x);   // row_shr:2
    x = dppmin<0x114>(x);   // row_shr:4
    x = dppmin<0x118>(x);   // row_shr:8
    x = dppmin<0x142>(x);   // row_bcast:15
    x = dppmin<0x143>(x);   // row_bcast:31 -> lane 63 has global min
    return __int_as_float(__builtin_amdgcn_readlane(__float_as_int(x), 63));
}

// ---- parallel auction initializer: 1024 threads (16 waves) per batch ----
// State: v (0-indexed, LDS), rowm[i]=col j (1-idx, 0=free), colm[j]=row.
// Invariants on exit (enforced by u-fixup): red(i,j)=C'(i,j)-u_i-v_j >= 0
// for all i,j (u_i = rowmin); red == 0 on every kept match.
__global__ __launch_bounds__(1024, 1)
void emd_auction_kernel(const __half* __restrict__ Dc,
                        const float* __restrict__ Vin,
                        const int* __restrict__ Iin,
                        float* __restrict__ Vw, float* __restrict__ Uw,
                        int* __restrict__ Cw, int* __restrict__ Rw) {
    __shared__ float v0[N];                 // column potentials, 0-indexed
    __shared__ int   rowm[N + 1];           // row -> col (1-idx), 0 = free
    __shared__ int   colm[N + 1];           // col -> row (1-idx), 0 = free
    __shared__ unsigned long long bid[N + 1];
    __shared__ int   qbuf[N];
    __shared__ int   qn;

    const int tid  = threadIdx.x;
    const int lane = tid & 63;
    const int wv   = tid >> 6;              // wave id 0..15
    const int b    = blockIdx.x;
    const __half* Db = Dc + ((size_t)b << 20);

    for (int t = tid; t <= N; t += 1024) { rowm[t] = 0; colm[t] = 0; bid[t] = 0ull; }
    for (int c = tid; c < N; c += 1024) v0[c] = Vin[b * N + c];
    __syncthreads();

    // greedy on tight edges (column -> its argmin row from colmin kernel)
    for (int c = tid; c < N; c += 1024) {
        int r = Iin[b * N + c];             // 1-indexed row
        int old = atomicCAS(&rowm[r], 0, c + 1);
        if (old == 0) colm[c + 1] = r;
    }
    __syncthreads();

    // per-wave row scan: red[k] = C'(i, lane*16+k) - v0[...]
    auto rowRed16 = [&](int i, float (&red)[16]) {
        const uint4* dr = (const uint4*)(Db + (size_t)(i - 1) * N);
        uint4 w0 = dr[lane * 2 + 0];
        uint4 w1 = dr[lane * 2 + 1];
        unsigned wb[8] = { w0.x, w0.y, w0.z, w0.w, w1.x, w1.y, w1.z, w1.w };
        const float4* vp = (const float4*)(v0 + lane * 16);   // 64B aligned
        float4 vv0 = vp[0], vv1 = vp[1], vv2 = vp[2], vv3 = vp[3];
        float vv[16] = { vv0.x, vv0.y, vv0.z, vv0.w, vv1.x, vv1.y, vv1.z, vv1.w,
                         vv2.x, vv2.y, vv2.z, vv2.w, vv3.x, vv3.y, vv3.z, vv3.w };
#pragma unroll
        for (int t = 0; t < 8; ++t) {
            __half2 hh = *reinterpret_cast<const __half2*>(&wb[t]);
            float2 f2 = __half22float2(hh);
            red[2 * t]     = f2.x - vv[2 * t];
            red[2 * t + 1] = f2.y - vv[2 * t + 1];
        }
    };

    // ---- bidding rounds ----
    for (int round = 0; round < AUC_ROUNDS; ++round) {
        if (tid == 0) qn = 0;
        __syncthreads();
        for (int i = tid + 1; i <= N; i += 1024)
            if (rowm[i] == 0) { int p = atomicAdd(&qn, 1); qbuf[p] = i; }
        __syncthreads();
        int nq = qn;
        if (nq == 0) break;

        for (int q = wv; q < nq; q += 16) {
            int i = qbuf[q];
            float red[16];
            rowRed16(i, red);
            // local (min, secmin, argmin-col 0-idx): 4 chains of depth 4
            float a1 = INFV, a2 = INFV; int ac = 0;
            float e1 = INFV, e2 = INFV; int ec = 0;
            float f1 = INFV, f2 = INFV; int fc = 0;
            float g1 = INFV, g2 = INFV; int gc = 0;
#pragma unroll
            for (int k = 0; k < 4; ++k) {
                float u0 = red[k];
                bool t0 = u0 < a1;
                a2 = t0 ? a1 : (u0 < a2 ? u0 : a2);
                ac = t0 ? (lane * 16 + k) : ac;  a1 = t0 ? u0 : a1;
                float u1 = red[k + 4];
                bool t1 = u1 < e1;
                e2 = t1 ? e1 : (u1 < e2 ? u1 : e2);
                ec = t1 ? (lane * 16 + k + 4) : ec;  e1 = t1 ? u1 : e1;
                float u2 = red[k + 8];
                bool t2 = u2 < f1;
                f2 = t2 ? f1 : (u2 < f2 ? u2 : f2);
                fc = t2 ? (lane * 16 + k + 8) : fc;  f1 = t2 ? u2 : f1;
                float u3 = red[k + 12];
                bool t3 = u3 < g1;
                g2 = t3 ? g1 : (u3 < g2 ? u3 : g2);
                gc = t3 ? (lane * 16 + k + 12) : gc;  g1 = t3 ? u3 : g1;
            }
            bool sae = e1 < a1;
            float ae1 = sae ? e1 : a1; int aec = sae ? ec : ac;
            float ae2 = fminf(fminf(a2, e2), sae ? a1 : e1);
            bool sfg = g1 < f1;
            float fg1 = sfg ? g1 : f1; int fgc = sfg ? gc : fc;
            float fg2 = fminf(fminf(f2, g2), sfg ? f1 : g1);
            bool sall = fg1 < ae1;
            float m1 = sall ? fg1 : ae1;
            int   c1 = sall ? fgc : aec;
            float m2 = fminf(fminf(ae2, fg2), sall ? ae1 : fg1);

            // wave argmin with payload (uniform results on all lanes)
            float gm1 = wave_min_f32(m1);
            unsigned long long wbm = __ballot(m1 == gm1);
            int wl = __ffsll((long long)wbm) - 1;
            float cand2 = (lane == wl) ? m2 : m1;
            float gm2 = wave_min_f32(cand2);
            int gcol = __builtin_amdgcn_readlane(c1, wl);   // 0-idx col
            float inc = gm2 - gm1;                          // >= 0

            if (lane == 0) {
                unsigned long long key =
                    ((unsigned long long)__float_as_uint(inc) << 32) |
                    (unsigned long long)(unsigned)i;
                atomicMax(&bid[gcol + 1], key);
            }
        }
        __syncthreads();

        // acceptance: column j takes its best bid; displaced row freed
        for (int j = tid + 1; j <= N; j += 1024) {
            unsigned long long bb = bid[j];
            if (bb != 0ull) {
                bid[j] = 0ull;
                int i = (int)(unsigned)(bb & 0xFFFFFFFFull);
                float inc = __uint_as_float((unsigned)(bb >> 32));
                int old = colm[j];
                colm[j] = i;
                rowm[i] = j;
                if (old) rowm[old] = 0;
                v0[j - 1] -= inc;
            }
        }
        __syncthreads();
    }

    // ---- u-fixup: u_i = rowmin(red_i) for all rows; drop non-tight ----
    for (int q = wv; q < N; q += 16) {
        int i = q + 1;
        float red[16];
        rowRed16(i, red);
        int j = rowm[i];                    // wave-uniform (LDS broadcast)
        // extract red at matched col before destroying red[]
        float rloc = red[0];
        int lo = 0, kk = 0;
        if (j) {
            lo = (j - 1) >> 4; kk = (j - 1) & 15;
#pragma unroll
            for (int k = 1; k < 16; ++k) if (k == kk) rloc = red[k];
        }
        // destructive tree min
#pragma unroll
        for (int s = 1; s < 16; s <<= 1) {
#pragma unroll
            for (int k = 0; k < 16; k += 2 * s)
                red[k] = fminf(red[k], red[k + s]);
        }
        float m = wave_min_f32(red[0]);
        if (j) {
            float rm = __int_as_float(
                __builtin_amdgcn_readlane(__float_as_int(rloc), lo));
            if (lane == 0 && rm != m) { rowm[i] = 0; colm[j] = 0; }
        }
        if (lane == 0) Uw[b * N + q] = m;
    }
    __syncthreads();

    // ---- write state for the SSP kernel ----
    for (int c = tid; c < N; c += 1024) {
        Vw[b * N + c] = v0[c];
        Cw[b * N + c] = colm[c + 1];
    }
    for (int t = tid; t < N; t += 1024) Rw[b * N + t] = rowm[t + 1];
}

struct Frag { uint4 w0, w1; float ur; float4 q; };

template<bool CACHED, bool PRE>
__global__ __launch_bounds__(64, 1)
void emd_jv_kernel(const float* __restrict__ S1,
                   const float* __restrict__ S2,
                   const __half* __restrict__ Dc,
                   const float* __restrict__ Vin,
                   const int*   __restrict__ Iin,
                   const float* __restrict__ Uw,
                   const int*   __restrict__ Cw,
                   const int*   __restrict__ Rw,
                   float* __restrict__ out) {
    __shared__ float4 s1u[N + 1];     // row coords (both modes; final fp32 sum)
    __shared__ float  u_lds[N + 1];   // row potentials
    __shared__ float  dentry[N + 1];  // D value when column settled
    __shared__ int    rowm[N + 1];    // row -> matched col (0 = free)

    const int lane = threadIdx.x;
    const int b = blockIdx.x;
    const float* s1g = S1 + (size_t)b * N * 3;
    const float* s2g = S2 + (size_t)b * N * 3;
    const __half* Db = CACHED ? (Dc + ((size_t)b << 20)) : (const __half*)0;
    const float NANF = __int_as_float(0x7fc00000);

    for (int t = lane; t < N; t += 64) {
        s1u[t + 1] = make_float4(s1g[3 * t], s1g[3 * t + 1], s1g[3 * t + 2], 0.0f);
        u_lds[t + 1] = PRE ? Uw[b * N + t] : 0.0f;
        rowm[t + 1] = PRE ? Rw[b * N + t] : 0;
    }
    if (lane == 0) { u_lds[0] = 0.0f; rowm[0] = 0; }

    // ---- per-lane column state: col j = c+1, c = lane*16+k ----
    float v[NSLOT];       // column potentials
    int   pr[NSLOT];      // matched row (0 = free)
    int   jpk[NSLOT];     // packed (pr<<11)|j
    float x2[NSLOT], y2[NSLOT], z2[NSLOT];  // S2 coords (final fp32 sum)

#pragma unroll
    for (int k = 0; k < NSLOT; ++k) {
        int pt = lane * NSLOT + k;
        x2[k] = s2g[3 * pt + 0];
        y2[k] = s2g[3 * pt + 1];
        z2[k] = s2g[3 * pt + 2];
    }

    if constexpr (PRE) {
#pragma unroll
        for (int k = 0; k < NSLOT; ++k) {
            int c = lane * NSLOT + k;
            v[k] = Vin[b * N + c];        // Vin = auction-updated v
            pr[k] = Cw[b * N + c];
            jpk[k] = (pr[k] << 11) | (c + 1);
        }
        __syncthreads();
    } else {
        int imin[NSLOT];
        if constexpr (CACHED) {
#pragma unroll
            for (int k = 0; k < NSLOT; ++k) {
                int c = lane * NSLOT + k;
                v[k] = Vin[b * N + c];
                imin[k] = Iin[b * N + c];
            }
        } else {
#pragma unroll
            for (int k = 0; k < NSLOT; ++k) { v[k] = INFV; imin[k] = 1; }
        }
        __syncthreads();

        if constexpr (!CACHED) {
            for (int r = 1; r <= N; ++r) {
                float4 qq = s1u[r];
#pragma unroll
                for (int k = 0; k < NSLOT; ++k) {
                    float dx = qq.x - x2[k], dy = qq.y - y2[k], dz = qq.z - z2[k];
                    float d2 = dx * dx + dy * dy + dz * dz;
                    bool upd = d2 < v[k];
                    v[k] = upd ? d2 : v[k];
                    imin[k] = upd ? r : imin[k];
                }
            }
#pragma unroll
            for (int k = 0; k < NSLOT; ++k) v[k] = sqrtf(v[k]);
        }

        // greedy matching on tight edges
#pragma unroll
        for (int k = 0; k < NSLOT; ++k) {
            int j = lane * NSLOT + k + 1;
            int r = imin[k];
            int old = atomicCAS(&rowm[r], 0, j);
            pr[k] = (old == 0) ? r : 0;
            jpk[k] = (pr[k] << 11) | j;
        }
        __syncthreads();
    }

    float minv[NSLOT];
    int   way[NSLOT];

    // issue row-r loads (cost-row fragment + u[r]); consumer waits only these
    auto issueLoads = [&](int rr) -> Frag {
        Frag F;
        if (CACHED) {
            const uint4* dr = (const uint4*)(Db + (size_t)(rr - 1) * N);
            F.w0 = dr[lane * 2 + 0];       // 8 halves
            F.w1 = dr[lane * 2 + 1];       // 8 halves
        } else {
            F.q = s1u[rr];
        }
        F.ur = u_lds[rr];
        return F;
    };

    auto applyFrag = [&](const Frag& F, int jpred, float Dh) {
        float base = Dh - F.ur;
        if (CACHED) {
            float h[NSLOT];
            const unsigned* w = (const unsigned*)&F.w0;   // w0,w1 contiguous
#pragma unroll
            for (int t = 0; t < 8; ++t) {
                unsigned word = w[t];
                __half2 hh = *reinterpret_cast<const __half2*>(&word);
                float2 f2 = __half22float2(hh);
                h[2 * t] = f2.x; h[2 * t + 1] = f2.y;
            }
#pragma unroll
            for (int k = 0; k < NSLOT; ++k) {
                float cur = (h[k] - v[k]) + base;
                bool upd = cur < minv[k];         // false for NaN (settled)
                minv[k] = upd ? cur : minv[k];
                way[k] = upd ? jpred : way[k];
            }
        } else {
#pragma unroll
            for (int k = 0; k < NSLOT; ++k) {
                float dx = F.q.x - x2[k], dy = F.q.y - y2[k], dz = F.q.z - z2[k];
                float d = sqrtf(dx * dx + dy * dy + dz * dz);
                float cur = (d - v[k]) + base;
                bool upd = cur < minv[k];
                minv[k] = upd ? cur : minv[k];
                way[k] = upd ? jpred : way[k];
            }
        }
    };

    // ---- successive shortest paths for free rows (exact on C') ----
    for (int i = 1; i <= N; ++i) {
        if (rowm[i] != 0) continue;

        unsigned used = 0u;
        float DT = 0.0f;
        int freecol = 0;
        int pred = 0;      // speculative prefetch: predicted next winner row
        Frag P;            // only read when pred != 0 (assigned then)

        Frag F0 = issueLoads(i);          // overlaps minv/way init
#pragma unroll
        for (int k = 0; k < NSLOT; ++k) { minv[k] = INFV; way[k] = 0; }
        applyFrag(F0, 0, 0.0f);

        int guard = 0;
        for (;;) {
            if (++guard > N + 4) break;
            // local argmin: 4 independent depth-4 chains + 2-level merge.
            float b0 = INFV, b1 = INFV, b2 = INFV, b3 = INFV;
            int   p0 = 0, p1 = 0, p2 = 0, p3 = 0;
#pragma unroll
            for (int k = 0; k < 4; ++k) {
                bool t0 = minv[k]      < b0;
                b0 = t0 ? minv[k]      : b0;  p0 = t0 ? jpk[k]      : p0;
                bool t1 = minv[k + 4]  < b1;
                b1 = t1 ? minv[k + 4]  : b1;  p1 = t1 ? jpk[k + 4]  : p1;
                bool t2 = minv[k + 8]  < b2;
                b2 = t2 ? minv[k + 8]  : b2;  p2 = t2 ? jpk[k + 8]  : p2;
                bool t3 = minv[k + 12] < b3;
                b3 = t3 ? minv[k + 12] : b3;  p3 = t3 ? jpk[k + 12] : p3;
            }
            bool m01 = b1 < b0;  float ba = m01 ? b1 : b0;  int pa = m01 ? p1 : p0;
            bool m23 = b3 < b2;  float bb = m23 ? b3 : b2;  int pb = m23 ? p3 : p2;
            bool mab = bb < ba;  float bestv = mab ? bb : ba;
            int bestjp = mab ? pb : pa;

            float gmin = wave_min_f32(bestv);
            if (!(gmin < INFV * 0.5f)) break;
            unsigned long long tm = __ballot(bestv == gmin);
            DT = gmin;
            freecol = 0;

            // 1) free-column short-circuit: zero expands if any tie is free
            {
                unsigned long long tf = tm;
                while (tf) {
                    int l = __ffsll((long long)tf) - 1;
                    tf &= tf - 1;
                    int jp = __builtin_amdgcn_readlane(bestjp, l);
                    if ((jp >> 11) == 0) { freecol = jp & 0x7FF; break; }
                }
            }
            if (freecol) break;

            // 2) settle all matched ties at gmin
            bool first = true;
            while (tm) {
                int l = __ffsll((long long)tm) - 1;
                tm &= tm - 1;
                int jp = __builtin_amdgcn_readlane(bestjp, l);
                int jj = jp & 0x7FF, rr = jp >> 11;
                Frag F;
                if (CACHED && first && pred != 0 && rr == pred) {
                    F = P;                         // prefetch hit: data resident
                } else {
                    F = issueLoads(rr);            // loads fly during marking
                }
                if (CACHED && first) {
                    // runner-up prefetch for the NEXT round; the wave-min +
                    // ballot here hides under the winner's L2 load latency.
                    float ru = (bestv == gmin) ? INFV : bestv;
                    float rmin = wave_min_f32(ru);
                    pred = 0;
                    if (rmin < INFV * 0.5f) {
                        unsigned long long rb = __ballot(ru == rmin);
                        int rl = __ffsll((long long)rb) - 1;
                        int rjp = __builtin_amdgcn_readlane(bestjp, rl);
                        int prr = rjp >> 11;
                        if (prr != 0) { pred = prr; P = issueLoads(prr); }
                    }
                }
                first = false;
                if (lane == 0) dentry[jj] = gmin;
                int cc = jj - 1, lo = cc >> 4, kk = cc & 15;
                bool mine = (lane == lo);
#pragma unroll
                for (int k = 0; k < NSLOT; ++k)
                    if (k == kk && mine) { minv[k] = NANF; used |= (1u << k); }
                applyFrag(F, jj, gmin);
            }
        }
        if (freecol == 0) continue;

        // deferred dual updates (pre-augment pr)
        if (lane == 0) u_lds[i] += DT;
#pragma unroll
        for (int k = 0; k < NSLOT; ++k) {
            if ((used >> k) & 1u) {
                int j = lane * NSLOT + k + 1;
                float dd = DT - dentry[j];
                v[k] -= dd;
                u_lds[pr[k]] += dd;      // distinct rows: race-free
            }
        }
        __syncthreads();

        // augment along alternating path (register p via readlanes)
        int j0 = freecol;
        int aguard = 0;
        while (j0 != 0) {
            if (++aguard > N + 4) break;
            int cc = j0 - 1;
            int lo = cc >> 4, kk = cc & 15;
            int wloc = way[0];
#pragma unroll
            for (int k = 1; k < NSLOT; ++k) if (k == kk) wloc = way[k];
            int j1 = __builtin_amdgcn_readlane(wloc, lo);
            int np;
            if (j1 == 0) np = i;
            else {
                int c1 = j1 - 1;
                int lo1 = c1 >> 4, kk1 = c1 & 15;
                int ploc = pr[0];
#pragma unroll
                for (int k = 1; k < NSLOT; ++k) if (k == kk1) ploc = pr[k];
                np = __builtin_amdgcn_readlane(ploc, lo1);
            }
            bool mine = (lane == lo);
#pragma unroll
            for (int k = 0; k < NSLOT; ++k)
                if (k == kk) {
                    if (mine) { pr[k] = np; jpk[k] = (np << 11) | j0; }
                }
            if (lane == 0) rowm[np] = j0;
            j0 = j1;
        }
        __syncthreads();
    }

    // ---- total matched cost: exact fp32 from coordinates ----
    float sum = 0.0f;
#pragma unroll
    for (int k = 0; k < NSLOT; ++k) {
        int r = pr[k] > 0 ? pr[k] : 1;
        float4 qq = s1u[r];
        float dx = qq.x - x2[k], dy = qq.y - y2[k], dz = qq.z - z2[k];
        sum += sqrtf(dx * dx + dy * dy + dz * dz);
    }
#pragma unroll
    for (int off = 32; off >= 1; off >>= 1) sum += __shfl_xor(sum, off);
    if (lane == 0) atomicAdd(out, sum * (1.0f / ((float)N * (float)BATCH)));
}

extern "C" void kernel_launch(void* const* d_in, const int* in_sizes, int n_in,
                              void* d_out, int out_size, void* d_ws, size_t ws_size,
                              hipStream_t stream) {
    const float* S1 = (const float*)d_in[0];
    const float* S2 = (const float*)d_in[1];
    float* out = (float*)d_out;

    size_t needD  = (size_t)BATCH * N * N * sizeof(__half);
    size_t vecB   = (size_t)BATCH * N * 4;            // one per-col/per-row array
    size_t needT  = needD + 2 * vecB;                 // V + I            (R8 tier)
    size_t needT2 = needD + 6 * vecB;                 // + Vw,Uw,Cw,Rw    (R13 tier)

    emd_zero_kernel<<<1, 1, 0, stream>>>(out);

    if (ws_size >= needT2) {
        __half* D  = (__half*)d_ws;
        float*  V  = (float*)((char*)d_ws + needD);
        int*    I  = (int*)((char*)V + vecB);
        float*  Vw = (float*)((char*)I + vecB);
        float*  Uw = (float*)((char*)Vw + vecB);
        int*    Cw = (int*)((char*)Uw + vecB);
        int*    Rw = (int*)((char*)Cw + vecB);
        emd_dist_kernel<<<BATCH * N, 256, 0, stream>>>(S1, S2, D);
        emd_colmin_kernel<<<BATCH * 4, 256, 0, stream>>>(D, V, I);
        emd_auction_kernel<<<BATCH, 1024, 0, stream>>>(D, V, I, Vw, Uw, Cw, Rw);
        emd_jv_kernel<true, true><<<BATCH, 64, 0, stream>>>(
            S1, S2, D, Vw, nullptr, Uw, Cw, Rw, out);
    } else if (ws_size >= needT) {
        __half* D = (__half*)d_ws;
        float*  V = (float*)((char*)d_ws + needD);
        int*    I = (int*)((char*)V + vecB);
        emd_dist_kernel<<<BATCH * N, 256, 0, stream>>>(S1, S2, D);
        emd_colmin_kernel<<<BATCH * 4, 256, 0, stream>>>(D, V, I);
        emd_jv_kernel<true, false><<<BATCH, 64, 0, stream>>>(
            S1, S2, D, V, I, nullptr, nullptr, nullptr, out);
    } else {
        emd_jv_kernel<false, false><<<BATCH, 64, 0, stream>>>(
            S1, S2, nullptr, nullptr, nullptr, nullptr, nullptr, nullptr, out);
    }
}